// Round 7
// baseline (1875.320 us; speedup 1.0000x reference)
//
#include <hip/hip_runtime.h>
#include <hip/hip_bf16.h>
#include <math.h>

using bf16 = __hip_bfloat16;

#define NB 1024   // batch
#define NT 64     // encoder length
#define ND 512    // input size D
#define NH 512    // hidden H
#define NC 96     // classes
#define NS 21     // decode steps
#define NDC 608   // D + C
#define NG 2048   // 4H
#define NWC 2688  // 512 + 2048 + 96 + 32 pad  (combo weight rows)

// ---- workspace layout (float offsets) ---- (round-5 layout)
#define OFF_HPB   0u          /* 16,777,216 : Hp bf16 [B*T,H] */
#define OFF_BHB   16777216u   /* 16,777,216 : batch_H bf16    */
#define OFF_C     33554432u   /* 524,288    : c fp32 [B,H]    */
#define OFF_HB16  34078720u   /* 262,144    : h bf16 [B,H]    */
#define OFF_PH    34340864u   /* 262,144    : ph bf16 [B,H]   */
#define OFF_CTXB  34865152u   /* 262,144    : ctx bf16 [B,D]  */
#define OFF_GATES 35127296u   /* 2,097,152  : gates_pre fp32 [B,4H] */
#define OFF_WIB   37224448u   /* 131,072    : Wi bf16 [512,512]     */
#define OFF_WHCG  37355520u   /* 688,128    : [Wh;Whh;Wg;pad] bf16 [2688,512] */
#define OFF_WIHB  38043648u   /* 524,288    : Wih[:, :512] bf16 [2048,512]    */
#define OFF_BIHH  38567936u   /* 2048 : bih+bhh fp32 */
#define OFF_BH_   38569984u   /* 512  : bh fp32      */
#define OFF_WS_   38570496u   /* 512  : Ws fp32      */
#define OFF_BG_   38571008u   /* 96   : bg fp32      */
#define OFF_OH    38571104u   /* 196,608 : onehotT fp32 [96][2048] */
#define WS_NEED_FLOATS 38767712u
#define WS_NEED_BYTES ((size_t)WS_NEED_FLOATS * 4u)

typedef __attribute__((ext_vector_type(8))) short bf16x8;
typedef __attribute__((ext_vector_type(4))) float f32x4;

__device__ __forceinline__ unsigned short f2bu(float f) {
    unsigned u = __float_as_uint(f);
    unsigned r = (u + 0x7fffu + ((u >> 16) & 1u)) >> 16;  // RNE
    return (unsigned short)r;
}
__device__ __forceinline__ float b2f(short s) {
    return __uint_as_float(((unsigned)(unsigned short)s) << 16);
}
__device__ __forceinline__ float fast_sigmoid(float x) {
    return 1.f / (1.f + __expf(-x));
}
__device__ __forceinline__ float fast_tanh(float x) {
    x = fminf(15.f, fmaxf(-15.f, x));
    float e = __expf(2.f * x);
    return (e - 1.f) / (e + 1.f);
}

// ---------------- merged conversion + state zeroing ----------------
#define BH_BLOCKS 32768u   /* (1024*64*512)/(256*4) */
#define W_ELEMS   2886752u
#define W_BLOCKS  11277u   /* ceil(W_ELEMS/256) */
#define Z_BLOCKS  768u     /* (524288+262144)/(256*4) */

__global__ __launch_bounds__(256) void conv_all(
    const float* __restrict__ bHsrc,
    const float* __restrict__ Wi, const float* __restrict__ Wh, const float* __restrict__ bh,
    const float* __restrict__ Ws, const float* __restrict__ Wih, const float* __restrict__ Whh,
    const float* __restrict__ bih, const float* __restrict__ bhh, const float* __restrict__ Wg,
    const float* __restrict__ bg, float* __restrict__ ws) {
    if (blockIdx.x < BH_BLOCKS) {
        unsigned short* dst = (unsigned short*)(ws + OFF_BHB);
        size_t i = ((size_t)blockIdx.x * 256 + threadIdx.x) * 4;
        float4 v = *(const float4*)(bHsrc + i);
        uint2 pk;
        pk.x = (unsigned)f2bu(v.x) | ((unsigned)f2bu(v.y) << 16);
        pk.y = (unsigned)f2bu(v.z) | ((unsigned)f2bu(v.w) << 16);
        *(uint2*)&dst[i] = pk;
        return;
    }
    if (blockIdx.x >= BH_BLOCKS + W_BLOCKS) {
        // zero c (fp32) + h (bf16): contiguous 786,432 floats at OFF_C
        unsigned iz = blockIdx.x - (BH_BLOCKS + W_BLOCKS);
        size_t o = OFF_C + ((size_t)iz * 256 + threadIdx.x) * 4;
        *(float4*)(ws + o) = (float4){0.f, 0.f, 0.f, 0.f};
        return;
    }
    unsigned i = (blockIdx.x - BH_BLOCKS) * 256u + threadIdx.x;
    if (i >= W_ELEMS) return;
    unsigned short* WiB  = (unsigned short*)(ws + OFF_WIB);
    unsigned short* WcB  = (unsigned short*)(ws + OFF_WHCG);
    unsigned short* WihB = (unsigned short*)(ws + OFF_WIHB);
    if (i < 262144u) {
        WiB[i] = f2bu(Wi[i]);
    } else if (i < 524288u) {
        unsigned j = i - 262144u;             // Wh -> rows 0..511
        WcB[j] = f2bu(Wh[j]);
    } else if (i < 1572864u) {
        unsigned j = i - 524288u;             // Whh -> rows 512..2559
        WcB[262144u + j] = f2bu(Whh[j]);
    } else if (i < 1622016u) {
        unsigned j = i - 1572864u;            // Wg -> rows 2560..2655
        WcB[1310720u + j] = f2bu(Wg[j]);
    } else if (i < 1638400u) {
        unsigned j = i - 1622016u;            // pad rows 2656..2687 = 0
        WcB[1359872u + j] = 0;
    } else if (i < 2686976u) {
        unsigned j = i - 1638400u;            // Wih[:, :512]
        unsigned row = j >> 9, col = j & 511u;
        WihB[j] = f2bu(Wih[row * NDC + col]);
    } else if (i < 2689024u) {
        unsigned j = i - 2686976u;
        ws[OFF_BIHH + j] = bih[j] + bhh[j];
    } else if (i < 2689536u) {
        unsigned j = i - 2689024u;
        ws[OFF_BH_ + j] = bh[j];
    } else if (i < 2690048u) {
        unsigned j = i - 2689536u;
        ws[OFF_WS_ + j] = Ws[j];
    } else if (i < 2690144u) {
        unsigned j = i - 2690048u;
        ws[OFF_BG_ + j] = bg[j];
    } else {
        unsigned j = i - 2690144u;            // onehotT[c][n] = Wih[n*608 + 512 + c]
        unsigned c = j >> 11, n = j & 2047u;
        ws[OFF_OH + j] = Wih[(size_t)n * NDC + ND + c];
    }
}

// ---------------- Hp GEMM (bf16 MFMA, 128x128 tile, reg-prefetch dbuf) ----------------
__global__ __launch_bounds__(256) void hp_gemm(const bf16* __restrict__ A,
                                               const bf16* __restrict__ B,
                                               bf16* __restrict__ outB) {
    __shared__ short As[128 * 40];
    __shared__ short Bs[128 * 40];
    const int tid = threadIdx.x;
    const int wave = tid >> 6, lane = tid & 63;
    const int wrow = wave >> 1, wcol = wave & 1;
    const int quad = lane >> 4, l16 = lane & 15;
    const int m0 = blockIdx.x * 128, n0 = blockIdx.y * 128;
    const int r0 = tid >> 2, r1 = (tid + 256) >> 2, c8 = tid & 3;
    f32x4 acc[4][4];
    #pragma unroll
    for (int mi = 0; mi < 4; ++mi)
        #pragma unroll
        for (int ni = 0; ni < 4; ++ni) acc[mi][ni] = (f32x4){0.f, 0.f, 0.f, 0.f};
    uint4 pa0, pa1, pb0, pb1;
    pa0 = *(const uint4*)&A[(size_t)(m0 + r0) * 512 + c8 * 8];
    pa1 = *(const uint4*)&A[(size_t)(m0 + r1) * 512 + c8 * 8];
    pb0 = *(const uint4*)&B[(size_t)(n0 + r0) * 512 + c8 * 8];
    pb1 = *(const uint4*)&B[(size_t)(n0 + r1) * 512 + c8 * 8];
    for (int k0 = 0; k0 < 512; k0 += 32) {
        *(uint4*)&As[r0 * 40 + c8 * 8] = pa0;
        *(uint4*)&As[r1 * 40 + c8 * 8] = pa1;
        *(uint4*)&Bs[r0 * 40 + c8 * 8] = pb0;
        *(uint4*)&Bs[r1 * 40 + c8 * 8] = pb1;
        __syncthreads();
        if (k0 < 480) {
            int kn = k0 + 32;
            pa0 = *(const uint4*)&A[(size_t)(m0 + r0) * 512 + kn + c8 * 8];
            pa1 = *(const uint4*)&A[(size_t)(m0 + r1) * 512 + kn + c8 * 8];
            pb0 = *(const uint4*)&B[(size_t)(n0 + r0) * 512 + kn + c8 * 8];
            pb1 = *(const uint4*)&B[(size_t)(n0 + r1) * 512 + kn + c8 * 8];
        }
        bf16x8 af[4], bfr[4];
        #pragma unroll
        for (int mi = 0; mi < 4; ++mi)
            af[mi] = *(const bf16x8*)&As[(wrow * 64 + mi * 16 + l16) * 40 + quad * 8];
        #pragma unroll
        for (int ni = 0; ni < 4; ++ni)
            bfr[ni] = *(const bf16x8*)&Bs[(wcol * 64 + ni * 16 + l16) * 40 + quad * 8];
        #pragma unroll
        for (int mi = 0; mi < 4; ++mi)
            #pragma unroll
            for (int ni = 0; ni < 4; ++ni)
                acc[mi][ni] = __builtin_amdgcn_mfma_f32_16x16x32_bf16(af[mi], bfr[ni],
                                                                      acc[mi][ni], 0, 0, 0);
        __syncthreads();
    }
    #pragma unroll
    for (int mi = 0; mi < 4; ++mi)
        #pragma unroll
        for (int ni = 0; ni < 4; ++ni)
            #pragma unroll
            for (int r = 0; r < 4; ++r) {
                int m = m0 + wrow * 64 + mi * 16 + quad * 4 + r;
                int n = n0 + wcol * 64 + ni * 16 + l16;
                outB[(size_t)m * 512 + n] = __float2bfloat16(acc[mi][ni][r]);
            }
}

// ---------------- combo GEMM: [ph(bf16) | gates_pre | probs(s-1)] = h @ [Wh;Whh;Wg]^T ----------------
// M=1024, N=2688, K=512. BM=128, BN=64. Reg-prefetch dbuf.
__global__ __launch_bounds__(256) void combo_gemm(const bf16* __restrict__ A,
                                                  const bf16* __restrict__ B,
                                                  const float* __restrict__ bh,
                                                  const float* __restrict__ bihh,
                                                  const float* __restrict__ bg,
                                                  unsigned short* __restrict__ phB,
                                                  float* __restrict__ gates,
                                                  float* __restrict__ out, int s) {
    __shared__ short As[128 * 40];
    __shared__ short Bs[64 * 40];
    const int tid = threadIdx.x;
    const int wave = tid >> 6, lane = tid & 63;
    const int wrow = wave >> 1, wcol = wave & 1;
    const int quad = lane >> 4, l16 = lane & 15;
    const int m0 = blockIdx.x * 128, n0 = blockIdx.y * 64;
    const int r0 = tid >> 2, r1 = (tid + 256) >> 2, c8 = tid & 3;
    f32x4 acc[4][2];
    #pragma unroll
    for (int mi = 0; mi < 4; ++mi)
        #pragma unroll
        for (int ni = 0; ni < 2; ++ni) acc[mi][ni] = (f32x4){0.f, 0.f, 0.f, 0.f};
    uint4 pa0, pa1, pb0;
    pa0 = *(const uint4*)&A[(size_t)(m0 + r0) * 512 + c8 * 8];
    pa1 = *(const uint4*)&A[(size_t)(m0 + r1) * 512 + c8 * 8];
    pb0 = *(const uint4*)&B[(size_t)(n0 + r0) * 512 + c8 * 8];
    for (int k0 = 0; k0 < 512; k0 += 32) {
        *(uint4*)&As[r0 * 40 + c8 * 8] = pa0;
        *(uint4*)&As[r1 * 40 + c8 * 8] = pa1;
        *(uint4*)&Bs[r0 * 40 + c8 * 8] = pb0;
        __syncthreads();
        if (k0 < 480) {
            int kn = k0 + 32;
            pa0 = *(const uint4*)&A[(size_t)(m0 + r0) * 512 + kn + c8 * 8];
            pa1 = *(const uint4*)&A[(size_t)(m0 + r1) * 512 + kn + c8 * 8];
            pb0 = *(const uint4*)&B[(size_t)(n0 + r0) * 512 + kn + c8 * 8];
        }
        bf16x8 af[4], bfr[2];
        #pragma unroll
        for (int mi = 0; mi < 4; ++mi)
            af[mi] = *(const bf16x8*)&As[(wrow * 64 + mi * 16 + l16) * 40 + quad * 8];
        #pragma unroll
        for (int ni = 0; ni < 2; ++ni)
            bfr[ni] = *(const bf16x8*)&Bs[(wcol * 32 + ni * 16 + l16) * 40 + quad * 8];
        #pragma unroll
        for (int mi = 0; mi < 4; ++mi)
            #pragma unroll
            for (int ni = 0; ni < 2; ++ni)
                acc[mi][ni] = __builtin_amdgcn_mfma_f32_16x16x32_bf16(af[mi], bfr[ni],
                                                                      acc[mi][ni], 0, 0, 0);
        __syncthreads();
    }
    #pragma unroll
    for (int mi = 0; mi < 4; ++mi) {
        #pragma unroll
        for (int ni = 0; ni < 2; ++ni) {
            #pragma unroll
            for (int r = 0; r < 4; ++r) {
                int m = m0 + wrow * 64 + mi * 16 + quad * 4 + r;
                int n = n0 + wcol * 32 + ni * 16 + l16;
                float v = acc[mi][ni][r];
                if (n < NH) {
                    phB[(size_t)m * NH + n] = f2bu(v + bh[n]);
                } else if (n < NH + NG) {
                    gates[(size_t)m * NG + (n - NH)] = v + bihh[n - NH];
                } else if (n < NH + NG + NC) {
                    if (s > 0)
                        out[(size_t)m * (NS * NC) + (s - 1) * NC + (n - NH - NG)] =
                            v + bg[n - NH - NG];
                }
            }
        }
    }
}

// ---------------- fused attention: score + softmax + context (bf16 out) ----------------
__global__ __launch_bounds__(256, 4) void attn_fused(const bf16* __restrict__ Hp,
                                                     const bf16* __restrict__ phB,
                                                     const float* __restrict__ Wsv,
                                                     const bf16* __restrict__ bH,
                                                     unsigned short* __restrict__ ctxB) {
    const int b = blockIdx.x;
    const int tid = threadIdx.x;
    const int wave = tid >> 6, lane = tid & 63;
    __shared__ float tr[64 * 65];
    __shared__ float salpha[NT];
    __shared__ float red[4][520];
    bf16x8 phv = *(const bf16x8*)(phB + (size_t)b * NH + lane * 8);
    float4 wsa = *(const float4*)(Wsv + lane * 8);
    float4 wsb = *(const float4*)(Wsv + lane * 8 + 4);
    float ph8[8], ws8[8];
    #pragma unroll
    for (int j = 0; j < 8; ++j) ph8[j] = b2f(phv[j]);
    ws8[0] = wsa.x; ws8[1] = wsa.y; ws8[2] = wsa.z; ws8[3] = wsa.w;
    ws8[4] = wsb.x; ws8[5] = wsb.y; ws8[6] = wsb.z; ws8[7] = wsb.w;
    const bf16* hpb = Hp + ((size_t)b * NT + wave * 16) * NH + lane * 8;
    float acc[16];
    #pragma unroll
    for (int i = 0; i < 16; ++i) {
        bf16x8 hv = *(const bf16x8*)(hpb + (size_t)i * NH);
        float s = 0.f;
        #pragma unroll
        for (int j = 0; j < 8; ++j) s += fast_tanh(b2f(hv[j]) + ph8[j]) * ws8[j];
        acc[i] = s;
    }
    #pragma unroll
    for (int i = 0; i < 16; ++i) tr[(wave * 16 + i) * 65 + lane] = acc[i];
    __syncthreads();
    if (tid < NT) {
        const float* row = &tr[tid * 65];
        float e = 0.f;
        #pragma unroll
        for (int j = 0; j < 64; ++j) e += row[j];
        float m = e;
        #pragma unroll
        for (int off = 32; off > 0; off >>= 1) m = fmaxf(m, __shfl_xor(m, off, 64));
        float ex = __expf(e - m);
        float ssum = ex;
        #pragma unroll
        for (int off = 32; off > 0; off >>= 1) ssum += __shfl_xor(ssum, off, 64);
        salpha[tid] = ex / ssum;
    }
    __syncthreads();
    {
        const bf16* bh = bH + ((size_t)b * NT + wave * 16) * ND + lane * 8;
        float a8[8];
        #pragma unroll
        for (int u = 0; u < 8; ++u) a8[u] = 0.f;
        #pragma unroll
        for (int i = 0; i < 16; ++i) {
            float al = salpha[wave * 16 + i];
            bf16x8 v = *(const bf16x8*)(bh + (size_t)i * ND);
            #pragma unroll
            for (int u = 0; u < 8; ++u) a8[u] = fmaf(al, b2f(v[u]), a8[u]);
        }
        #pragma unroll
        for (int u = 0; u < 8; ++u) red[wave][lane * 8 + u] = a8[u];
    }
    __syncthreads();
    for (int d = tid; d < ND; d += 256) {
        float sum = red[0][d] + red[1][d] + red[2][d] + red[3][d];
        ctxB[(size_t)b * ND + d] = f2bu(sum);
    }
}

// ---------------- gates GEMM (K=512) + LSTM pointwise (gate-grouped, dbuf) ----------------
__global__ __launch_bounds__(256) void gates_lstm(const bf16* __restrict__ ctxB,
                                                  const bf16* __restrict__ WihB,
                                                  const float* __restrict__ gates_pre,
                                                  const float* __restrict__ onehotT,
                                                  const int* __restrict__ text, int s,
                                                  float* __restrict__ c,
                                                  unsigned short* __restrict__ hB) {
    __shared__ float smem[4 * 32 * 65];       // 33,280 B; unioned with staging
    short* As = (short*)smem;                 // 32 rows * 40
    short* Bs = As + 32 * 40;                 // 256 rows * 40
    float* ex = smem;                         // [4][32][65] after the k-loop
    const int tid = threadIdx.x;
    const int g = tid >> 6, lane = tid & 63;
    const int quad = lane >> 4, l16 = lane & 15;
    const int m0 = blockIdx.x * 32, kp0 = blockIdx.y * 64;
    const int c8 = tid & 3;
    const int ar = tid >> 2;                  // valid when tid<128
    int br[4];
    #pragma unroll
    for (int l = 0; l < 4; ++l) {
        int row = (tid + l * 256) >> 2;
        br[l] = (row >> 6) * 512 + kp0 + (row & 63);
    }
    f32x4 acc[2][4];
    #pragma unroll
    for (int mi = 0; mi < 2; ++mi)
        #pragma unroll
        for (int ni = 0; ni < 4; ++ni) acc[mi][ni] = (f32x4){0.f, 0.f, 0.f, 0.f};
    uint4 pa, pb[4];
    if (tid < 128) pa = *(const uint4*)&ctxB[(size_t)(m0 + ar) * 512 + c8 * 8];
    #pragma unroll
    for (int l = 0; l < 4; ++l)
        pb[l] = *(const uint4*)&WihB[(size_t)br[l] * 512 + c8 * 8];
    for (int k0 = 0; k0 < 512; k0 += 32) {
        if (tid < 128) *(uint4*)&As[ar * 40 + c8 * 8] = pa;
        #pragma unroll
        for (int l = 0; l < 4; ++l) {
            int row = (tid + l * 256) >> 2;
            *(uint4*)&Bs[row * 40 + c8 * 8] = pb[l];
        }
        __syncthreads();
        if (k0 < 480) {
            int kn = k0 + 32;
            if (tid < 128) pa = *(const uint4*)&ctxB[(size_t)(m0 + ar) * 512 + kn + c8 * 8];
            #pragma unroll
            for (int l = 0; l < 4; ++l)
                pb[l] = *(const uint4*)&WihB[(size_t)br[l] * 512 + kn + c8 * 8];
        }
        bf16x8 af[2], bfr[4];
        #pragma unroll
        for (int mi = 0; mi < 2; ++mi)
            af[mi] = *(const bf16x8*)&As[(mi * 16 + l16) * 40 + quad * 8];
        #pragma unroll
        for (int ni = 0; ni < 4; ++ni)
            bfr[ni] = *(const bf16x8*)&Bs[(g * 64 + ni * 16 + l16) * 40 + quad * 8];
        #pragma unroll
        for (int mi = 0; mi < 2; ++mi)
            #pragma unroll
            for (int ni = 0; ni < 4; ++ni)
                acc[mi][ni] = __builtin_amdgcn_mfma_f32_16x16x32_bf16(af[mi], bfr[ni],
                                                                      acc[mi][ni], 0, 0, 0);
        __syncthreads();
    }
    #pragma unroll
    for (int mi = 0; mi < 2; ++mi)
        #pragma unroll
        for (int ni = 0; ni < 4; ++ni)
            #pragma unroll
            for (int r = 0; r < 4; ++r) {
                int ml = mi * 16 + quad * 4 + r;
                int nl = ni * 16 + l16;
                ex[g * 2080 + ml * 65 + nl] = acc[mi][ni][r];
            }
    __syncthreads();
    #pragma unroll 1
    for (int t = 0; t < 8; ++t) {
        int idx = tid + t * 256;
        int ml = idx >> 6, kl = idx & 63;
        int m = m0 + ml, kp = kp0 + kl;
        int tb = text[m * NS + s];
        const float* oh = onehotT + (size_t)tb * NG;
        const float* gp = gates_pre + (size_t)m * NG;
        float ig = fast_sigmoid(ex[0 * 2080 + ml * 65 + kl] + gp[kp] + oh[kp]);
        float fg = fast_sigmoid(ex[1 * 2080 + ml * 65 + kl] + gp[NH + kp] + oh[NH + kp]);
        float gg = fast_tanh(ex[2 * 2080 + ml * 65 + kl] + gp[2 * NH + kp] + oh[2 * NH + kp]);
        float og = fast_sigmoid(ex[3 * 2080 + ml * 65 + kl] + gp[3 * NH + kp] + oh[3 * NH + kp]);
        float cn = fg * c[(size_t)m * NH + kp] + ig * gg;
        float hn = og * fast_tanh(cn);
        c[(size_t)m * NH + kp] = cn;
        hB[(size_t)m * NH + kp] = f2bu(hn);
    }
}

// ---------------- final generator: probs row 20 = h @ Wg^T + bg ----------------
__global__ __launch_bounds__(256) void final_gen(const bf16* __restrict__ hB,
                                                 const bf16* __restrict__ WgB,
                                                 const float* __restrict__ bg,
                                                 float* __restrict__ out) {
    const int b = blockIdx.x;
    const int tid = threadIdx.x;
    __shared__ float hsm[NH];
    for (int k = tid; k < NH; k += 256) hsm[k] = b2f(*(const short*)&hB[(size_t)b * NH + k]);
    __syncthreads();
    if (tid < 2 * NC) {
        int oc = tid >> 1, half = tid & 1;
        const bf16* w = WgB + (size_t)oc * NH + half * 256;
        float a = 0.f;
        #pragma unroll 4
        for (int j = 0; j < 32; ++j) {
            bf16x8 w8 = *(const bf16x8*)(w + j * 8);
            #pragma unroll
            for (int u = 0; u < 8; ++u)
                a = fmaf(b2f(w8[u]), hsm[half * 256 + j * 8 + u], a);
        }
        a += __shfl_xor(a, 1, 64);
        if (half == 0)
            out[(size_t)b * (NS * NC) + 20 * NC + oc] = a + bg[oc];
    }
}

extern "C" void kernel_launch(void* const* d_in, const int* in_sizes, int n_in,
                              void* d_out, int out_size, void* d_ws, size_t ws_size,
                              hipStream_t stream) {
    if (ws_size < WS_NEED_BYTES) {
        hipMemsetAsync(d_out, 0x7F, (size_t)out_size * 4, stream);
        return;
    }
    float* ws = (float*)d_ws;
    bf16* HpB  = (bf16*)(ws + OFF_HPB);
    bf16* bHB  = (bf16*)(ws + OFF_BHB);
    float* cb  = ws + OFF_C;
    bf16* hB   = (bf16*)(ws + OFF_HB16);
    bf16* phB  = (bf16*)(ws + OFF_PH);
    bf16* ctxB = (bf16*)(ws + OFF_CTXB);
    float* gb  = ws + OFF_GATES;
    bf16* WiB  = (bf16*)(ws + OFF_WIB);
    bf16* WcB  = (bf16*)(ws + OFF_WHCG);
    bf16* WihB = (bf16*)(ws + OFF_WIHB);
    const int* text = (const int*)d_in[1];
    float* out = (float*)d_out;

    conv_all<<<BH_BLOCKS + W_BLOCKS + Z_BLOCKS, 256, 0, stream>>>(
        (const float*)d_in[0],
        (const float*)d_in[2], (const float*)d_in[3], (const float*)d_in[4],
        (const float*)d_in[5], (const float*)d_in[6], (const float*)d_in[7],
        (const float*)d_in[8], (const float*)d_in[9], (const float*)d_in[10],
        (const float*)d_in[11], ws);

    // Hp(bf16) = batch_H @ Wi^T
    hp_gemm<<<dim3(NB * NT / 128, ND / 128), 256, 0, stream>>>(bHB, WiB, HpB);

    for (int s = 0; s < NS; ++s) {
        combo_gemm<<<dim3(NB / 128, NWC / 64), 256, 0, stream>>>(
            hB, WcB, ws + OFF_BH_, ws + OFF_BIHH, ws + OFF_BG_,
            (unsigned short*)phB, gb, out, s);
        attn_fused<<<NB, 256, 0, stream>>>(HpB, phB, ws + OFF_WS_, bHB,
                                           (unsigned short*)ctxB);
        gates_lstm<<<dim3(NB / 32, NH / 64), 256, 0, stream>>>(
            ctxB, WihB, gb, ws + OFF_OH, text, s, cb, (unsigned short*)hB);
    }
    final_gen<<<NB, 256, 0, stream>>>(hB, WcB + (size_t)2560 * 512, ws + OFF_BG_, out);
}